// Round 1
// baseline (4186.993 us; speedup 1.0000x reference)
//
#include <hip/hip_runtime.h>

#define B_ 128
#define S_ 1024
#define H_ 256
#define V_ 256

// ---------------------------------------------------------------------------
// K1: A[v,h] = sum_k embed[v,k] * Wxh[h,k] + bxh[h] + bhh[h]
// ---------------------------------------------------------------------------
__global__ __launch_bounds__(256) void prep_A(const float* __restrict__ embed,
                                              const float* __restrict__ Wxh,
                                              const float* __restrict__ bxh,
                                              const float* __restrict__ bhh,
                                              float* __restrict__ A) {
  const int v = blockIdx.x, h = threadIdx.x;
  const float4* e4 = reinterpret_cast<const float4*>(embed + v * H_);
  const float4* w4 = reinterpret_cast<const float4*>(Wxh + h * H_);
  float p0 = 0.f, p1 = 0.f, p2 = 0.f, p3 = 0.f;
#pragma unroll
  for (int q = 0; q < H_ / 4; ++q) {
    float4 a = e4[q], w = w4[q];
    p0 += a.x * w.x;
    p1 += a.y * w.y;
    p2 += a.z * w.z;
    p3 += a.w * w.w;
  }
  A[v * H_ + h] = (p0 + p1) + (p2 + p3) + bxh[h] + bhh[h];
}

// ---------------------------------------------------------------------------
// K2: Elman recurrence. One workgroup per batch; thread t owns feature t and
// holds Whh row t in 256 VGPRs. h double-buffered in LDS (broadcast reads).
// hs is written into d_out (reused as scratch; same size as final out).
// ---------------------------------------------------------------------------
__global__ __launch_bounds__(256, 1) void rnn_fwd(const int* __restrict__ x,
                                                  const float* __restrict__ A,
                                                  const float* __restrict__ Whh,
                                                  float* __restrict__ hs) {
  const int t = threadIdx.x, b = blockIdx.x;
  float4 w[H_ / 4];
#pragma unroll
  for (int q = 0; q < H_ / 4; ++q)
    w[q] = reinterpret_cast<const float4*>(Whh + t * H_)[q];

  __shared__ __align__(16) float hbuf[2][H_];
  hbuf[0][t] = 0.f;
  const int* xb = x + b * S_;
  float* hsb = hs + (size_t)b * S_ * H_;
  int tok = xb[0];
  float a_next = A[tok * H_ + t];
  __syncthreads();

  for (int s = 0; s < S_; ++s) {
    const float* hb = hbuf[s & 1];
    float acc = a_next;
    if (s + 1 < S_) {
      int tok2 = xb[s + 1];
      a_next = A[tok2 * H_ + t];
    }
    float p0 = 0.f, p1 = 0.f, p2 = 0.f, p3 = 0.f;
    float p4 = 0.f, p5 = 0.f, p6 = 0.f, p7 = 0.f;
#pragma unroll
    for (int q = 0; q < H_ / 8; ++q) {
      float4 wa = w[2 * q], wb = w[2 * q + 1];
      float4 ha = *reinterpret_cast<const float4*>(&hb[8 * q]);
      float4 hc = *reinterpret_cast<const float4*>(&hb[8 * q + 4]);
      p0 += wa.x * ha.x;
      p1 += wa.y * ha.y;
      p2 += wa.z * ha.z;
      p3 += wa.w * ha.w;
      p4 += wb.x * hc.x;
      p5 += wb.y * hc.y;
      p6 += wb.z * hc.z;
      p7 += wb.w * hc.w;
    }
    float hv = tanhf(acc + ((p0 + p1) + (p2 + p3)) + ((p4 + p5) + (p6 + p7)));
    hsb[s * H_ + t] = hv;
    hbuf[(s + 1) & 1][t] = hv;  // other buffer: no race with readers of hb
    __syncthreads();
  }
}

// ---------------------------------------------------------------------------
// K3: online softmax over s for scores = hs @ Wattn^T + battn, fused with the
// context numerator. Each block handles (batch, half-of-sequence); thread t
// owns feature t with Wattn row t in VGPRs. Partial (m, l, N) per block.
// ---------------------------------------------------------------------------
__global__ __launch_bounds__(256, 1) void attn_part_k(const float* __restrict__ hs,
                                                      const float* __restrict__ Wattn,
                                                      const float* __restrict__ battn,
                                                      float* __restrict__ part) {
  const int t = threadIdx.x;
  const int b = blockIdx.x >> 1, half = blockIdx.x & 1;
  float4 w[H_ / 4];
#pragma unroll
  for (int q = 0; q < H_ / 4; ++q)
    w[q] = reinterpret_cast<const float4*>(Wattn + t * H_)[q];

  __shared__ __align__(16) float hrow[2][H_];
  const float* base = hs + ((size_t)b * S_ + (size_t)half * (S_ / 2)) * H_;
  const float bat = battn[t];
  float m = -3.0e38f, l = 0.f, N = 0.f;
  hrow[0][t] = base[t];
  __syncthreads();

  for (int i = 0; i < S_ / 2; ++i) {
    float nxt = 0.f;
    if (i + 1 < S_ / 2) nxt = base[(size_t)(i + 1) * H_ + t];
    const float* hb = hrow[i & 1];
    float hval = hb[t];
    float p0 = 0.f, p1 = 0.f, p2 = 0.f, p3 = 0.f;
    float p4 = 0.f, p5 = 0.f, p6 = 0.f, p7 = 0.f;
#pragma unroll
    for (int q = 0; q < H_ / 8; ++q) {
      float4 wa = w[2 * q], wb = w[2 * q + 1];
      float4 ha = *reinterpret_cast<const float4*>(&hb[8 * q]);
      float4 hc = *reinterpret_cast<const float4*>(&hb[8 * q + 4]);
      p0 += wa.x * ha.x;
      p1 += wa.y * ha.y;
      p2 += wa.z * ha.z;
      p3 += wa.w * ha.w;
      p4 += wb.x * hc.x;
      p5 += wb.y * hc.y;
      p6 += wb.z * hc.z;
      p7 += wb.w * hc.w;
    }
    float sc = bat + ((p0 + p1) + (p2 + p3)) + ((p4 + p5) + (p6 + p7));
    float mn = fmaxf(m, sc);
    float scale = __expf(m - mn);
    float e = __expf(sc - mn);
    l = l * scale + e;
    N = N * scale + e * hval;
    m = mn;
    hrow[(i + 1) & 1][t] = nxt;
    __syncthreads();
  }
  float* pb = part + (size_t)(b * 2 + half) * 3 * H_;
  pb[0 * H_ + t] = m;
  pb[1 * H_ + t] = l;
  pb[2 * H_ + t] = N;
}

// ---------------------------------------------------------------------------
// K3b: merge the two sequence halves, produce context[b,h] = N/l.
// ---------------------------------------------------------------------------
__global__ __launch_bounds__(256) void attn_merge(const float* __restrict__ part,
                                                  float* __restrict__ ctx) {
  const int b = blockIdx.x, t = threadIdx.x;
  const float* p1 = part + (size_t)(b * 2 + 0) * 3 * H_;
  const float* p2 = part + (size_t)(b * 2 + 1) * 3 * H_;
  float m1 = p1[t], l1 = p1[H_ + t], N1 = p1[2 * H_ + t];
  float m2 = p2[t], l2 = p2[H_ + t], N2 = p2[2 * H_ + t];
  float m = fmaxf(m1, m2);
  float a1 = __expf(m1 - m), a2 = __expf(m2 - m);
  float l = l1 * a1 + l2 * a2;
  float N = N1 * a1 + N2 * a2;
  ctx[b * H_ + t] = N / l;
}

// ---------------------------------------------------------------------------
// K4: out = (hs + context) @ Wfc^T + bfc, computed in-place over d_out.
// Each block: 32 rows staged (+context) into LDS, thread t owns column v=t
// with Wfc row t in VGPRs. In-place safe: tile fully staged before writes.
// ---------------------------------------------------------------------------
__global__ __launch_bounds__(256, 1) void out_gemm(float* __restrict__ data,
                                                   const float* __restrict__ Wfc,
                                                   const float* __restrict__ bfc,
                                                   const float* __restrict__ ctx) {
  const int t = threadIdx.x;
  const int tile = blockIdx.x;  // B*S/32 tiles, all rows in same batch
  const int b = tile >> 5;
  const size_t r0 = (size_t)tile * 32;
  float4 w[H_ / 4];
#pragma unroll
  for (int q = 0; q < H_ / 4; ++q)
    w[q] = reinterpret_cast<const float4*>(Wfc + t * H_)[q];

  __shared__ __align__(16) float comb[32][H_];
  const float cx = ctx[b * H_ + t];
#pragma unroll
  for (int r = 0; r < 32; ++r) comb[r][t] = data[(r0 + r) * H_ + t] + cx;
  __syncthreads();

  const float bv = bfc[t];
#pragma unroll 1
  for (int r = 0; r < 32; r += 4) {
    float s0 = bv, s1 = bv, s2 = bv, s3 = bv;
#pragma unroll
    for (int q = 0; q < H_ / 4; ++q) {
      float4 wv = w[q];
      float4 c0 = *reinterpret_cast<const float4*>(&comb[r + 0][4 * q]);
      float4 c1 = *reinterpret_cast<const float4*>(&comb[r + 1][4 * q]);
      float4 c2 = *reinterpret_cast<const float4*>(&comb[r + 2][4 * q]);
      float4 c3 = *reinterpret_cast<const float4*>(&comb[r + 3][4 * q]);
      s0 += wv.x * c0.x; s0 += wv.y * c0.y; s0 += wv.z * c0.z; s0 += wv.w * c0.w;
      s1 += wv.x * c1.x; s1 += wv.y * c1.y; s1 += wv.z * c1.z; s1 += wv.w * c1.w;
      s2 += wv.x * c2.x; s2 += wv.y * c2.y; s2 += wv.z * c2.z; s2 += wv.w * c2.w;
      s3 += wv.x * c3.x; s3 += wv.y * c3.y; s3 += wv.z * c3.z; s3 += wv.w * c3.w;
    }
    data[(r0 + r + 0) * H_ + t] = s0;
    data[(r0 + r + 1) * H_ + t] = s1;
    data[(r0 + r + 2) * H_ + t] = s2;
    data[(r0 + r + 3) * H_ + t] = s3;
  }
}

// ---------------------------------------------------------------------------
extern "C" void kernel_launch(void* const* d_in, const int* in_sizes, int n_in,
                              void* d_out, int out_size, void* d_ws, size_t ws_size,
                              hipStream_t stream) {
  const int* x = (const int*)d_in[0];
  const float* embed = (const float*)d_in[1];
  const float* Wxh = (const float*)d_in[2];
  const float* bxh = (const float*)d_in[3];
  const float* Whh = (const float*)d_in[4];
  const float* bhh = (const float*)d_in[5];
  const float* Wattn = (const float*)d_in[6];
  const float* battn = (const float*)d_in[7];
  const float* Wfc = (const float*)d_in[8];
  const float* bfc = (const float*)d_in[9];
  float* out = (float*)d_out;

  float* A = (float*)d_ws;            // V*H
  float* part = A + V_ * H_;          // B*2*3*H
  float* ctx = part + B_ * 2 * 3 * H_;  // B*H

  prep_A<<<V_, H_, 0, stream>>>(embed, Wxh, bxh, bhh, A);
  rnn_fwd<<<B_, H_, 0, stream>>>(x, A, Whh, out);
  attn_part_k<<<B_ * 2, H_, 0, stream>>>(out, Wattn, battn, part);
  attn_merge<<<B_, H_, 0, stream>>>(part, ctx);
  out_gemm<<<B_ * S_ / 32, H_, 0, stream>>>(out, Wfc, bfc, ctx);
}

// Round 2
// 1618.358 us; speedup vs baseline: 2.5872x; 2.5872x over previous
//
#include <hip/hip_runtime.h>

#define B_ 128
#define S_ 1024
#define H_ 256
#define V_ 256
#define HP 68  // padded chunk stride in floats (64 + 4): staggers the 4 k-chunks across bank groups

// padded LDS index for hidden element o
#define SWI(o) ((((o) >> 6) * HP) + ((o) & 63))

// quad (4-lane) all-reduce add via DPP (VALU pipe; keeps LDS pipe free)
__device__ __forceinline__ float quad_reduce_add(float v) {
  int a = __builtin_amdgcn_update_dpp(0, __float_as_int(v), 0xB1, 0xF, 0xF, true);  // quad_perm [1,0,3,2]
  v += __int_as_float(a);
  a = __builtin_amdgcn_update_dpp(0, __float_as_int(v), 0x4E, 0xF, 0xF, true);      // quad_perm [2,3,0,1]
  v += __int_as_float(a);
  return v;
}

// ---------------------------------------------------------------------------
// K1: A[v,h] = embed[v,:]·Wxh[h,:] + bxh[h] + bhh[h]
// 512 threads: thread=(hg,qq): outputs {hg, hg+128}, k-chunk qq*64..+64.
// ---------------------------------------------------------------------------
__global__ __launch_bounds__(512, 2) void prep_A(const float* __restrict__ embed,
                                                 const float* __restrict__ Wxh,
                                                 const float* __restrict__ bxh,
                                                 const float* __restrict__ bhh,
                                                 float* __restrict__ A) {
  const int v = blockIdx.x, t = threadIdx.x;
  const int qq = t & 3, hg = t >> 2;
  const int h0 = hg, h1 = hg + 128;
  const int kb = qq * 64;

  __shared__ __align__(16) float erow[4 * HP];
  if (t < 64)
    reinterpret_cast<float4*>(&erow[(t >> 4) * HP])[t & 15] =
        reinterpret_cast<const float4*>(embed + v * H_)[t];

  float4 w0[16], w1[16];
  {
    const float4* W0 = reinterpret_cast<const float4*>(Wxh + h0 * H_ + kb);
    const float4* W1 = reinterpret_cast<const float4*>(Wxh + h1 * H_ + kb);
#pragma unroll
    for (int q = 0; q < 16; ++q) { w0[q] = W0[q]; w1[q] = W1[q]; }
  }
  __syncthreads();

  const float4* e4 = reinterpret_cast<const float4*>(&erow[qq * HP]);
  float4 p0 = make_float4(0, 0, 0, 0), p1 = make_float4(0, 0, 0, 0);
#pragma unroll
  for (int q = 0; q < 16; ++q) {
    float4 hq = e4[q];
    p0.x += w0[q].x * hq.x; p0.y += w0[q].y * hq.y;
    p0.z += w0[q].z * hq.z; p0.w += w0[q].w * hq.w;
    p1.x += w1[q].x * hq.x; p1.y += w1[q].y * hq.y;
    p1.z += w1[q].z * hq.z; p1.w += w1[q].w * hq.w;
  }
  float d0 = quad_reduce_add((p0.x + p0.y) + (p0.z + p0.w));
  float d1 = quad_reduce_add((p1.x + p1.y) + (p1.z + p1.w));
  if (qq == 0) {
    A[v * H_ + h0] = d0 + bxh[h0] + bhh[h0];
    A[v * H_ + h1] = d1 + bxh[h1] + bhh[h1];
  }
}

// ---------------------------------------------------------------------------
// K2: Elman recurrence, one block per batch. 512 threads: thread=(og,qq) owns
// outputs {og, og+128} with k-chunk qq. Weights = 128 VGPR floats (no spill).
// h double-buffered in chunk-staggered LDS; DPP quad reduce; one barrier/step.
// ---------------------------------------------------------------------------
__global__ __launch_bounds__(512, 2) void rnn_fwd(const int* __restrict__ x,
                                                  const float* __restrict__ A,
                                                  const float* __restrict__ Whh,
                                                  float* __restrict__ hs) {
  const int t = threadIdx.x, b = blockIdx.x;
  const int qq = t & 3, og = t >> 2;  // og in [0,128)
  const int o0 = og, o1 = og + 128;
  const int kb = qq * 64;

  float4 w0[16], w1[16];
  {
    const float4* W0 = reinterpret_cast<const float4*>(Whh + o0 * H_ + kb);
    const float4* W1 = reinterpret_cast<const float4*>(Whh + o1 * H_ + kb);
#pragma unroll
    for (int q = 0; q < 16; ++q) { w0[q] = W0[q]; w1[q] = W1[q]; }
  }

  __shared__ __align__(16) float hbuf[2][4 * HP];
  if (t < H_) hbuf[0][SWI(t)] = 0.f;
  const int* xb = x + b * S_;
  float* hsb = hs + (size_t)b * S_ * H_;
  float a0 = 0.f, a1 = 0.f;
  if (qq == 0) {
    int tok = xb[0];
    a0 = A[tok * H_ + o0];
    a1 = A[tok * H_ + o1];
  }
  __syncthreads();

  for (int s = 0; s < S_; ++s) {
    const float4* hb4 = reinterpret_cast<const float4*>(&hbuf[s & 1][qq * HP]);
    float a0n = 0.f, a1n = 0.f;
    if (qq == 0 && s + 1 < S_) {  // prefetch next token's input projection
      int tok = xb[s + 1];
      a0n = A[tok * H_ + o0];
      a1n = A[tok * H_ + o1];
    }
    float4 p0 = make_float4(0, 0, 0, 0), p1 = make_float4(0, 0, 0, 0);
#pragma unroll
    for (int q = 0; q < 16; ++q) {
      float4 hq = hb4[q];
      p0.x += w0[q].x * hq.x; p0.y += w0[q].y * hq.y;
      p0.z += w0[q].z * hq.z; p0.w += w0[q].w * hq.w;
      p1.x += w1[q].x * hq.x; p1.y += w1[q].y * hq.y;
      p1.z += w1[q].z * hq.z; p1.w += w1[q].w * hq.w;
    }
    float d0 = quad_reduce_add((p0.x + p0.y) + (p0.z + p0.w));
    float d1 = quad_reduce_add((p1.x + p1.y) + (p1.z + p1.w));
    if (qq == 0) {
      float hv0 = tanhf(d0 + a0);
      float hv1 = tanhf(d1 + a1);
      float* nb = hbuf[(s + 1) & 1];  // writes target buffer not being read this step
      nb[SWI(o0)] = hv0;
      nb[SWI(o1)] = hv1;
      hsb[s * H_ + o0] = hv0;
      hsb[s * H_ + o1] = hv1;
    }
    a0 = a0n; a1 = a1n;
    __syncthreads();
  }
}

// ---------------------------------------------------------------------------
// K3: fused scores + online softmax + context numerator. Block = (batch,
// seq-quarter); 512 blocks -> 2/CU. Same (og,qq) split as rnn_fwd. Online
// state kept redundantly on all 4 qq lanes (DPP reduce is symmetric).
// ---------------------------------------------------------------------------
__global__ __launch_bounds__(512, 2) void attn_part_k(const float* __restrict__ hs,
                                                      const float* __restrict__ Wattn,
                                                      const float* __restrict__ battn,
                                                      float* __restrict__ part) {
  const int t = threadIdx.x;
  const int b = blockIdx.x >> 2, quarter = blockIdx.x & 3;
  const int qq = t & 3, og = t >> 2;
  const int o0 = og, o1 = og + 128;
  const int kb = qq * 64;

  float4 w0[16], w1[16];
  {
    const float4* W0 = reinterpret_cast<const float4*>(Wattn + o0 * H_ + kb);
    const float4* W1 = reinterpret_cast<const float4*>(Wattn + o1 * H_ + kb);
#pragma unroll
    for (int q = 0; q < 16; ++q) { w0[q] = W0[q]; w1[q] = W1[q]; }
  }

  __shared__ __align__(16) float hrow[2][4 * HP];
  const float* base = hs + ((size_t)b * S_ + (size_t)quarter * (S_ / 4)) * H_;
  if (t < 64) {
    float4 v = reinterpret_cast<const float4*>(base)[t];
    reinterpret_cast<float4*>(&hrow[0][(t >> 4) * HP])[t & 15] = v;
  }
  const float ba0 = battn[o0], ba1 = battn[o1];
  float m0 = -3.0e38f, l0 = 0.f, N0 = 0.f;
  float m1 = -3.0e38f, l1 = 0.f, N1 = 0.f;
  __syncthreads();

  for (int i = 0; i < S_ / 4; ++i) {
    float4 nv;
    const bool pf = (t < 64) && (i + 1 < S_ / 4);
    if (pf) nv = reinterpret_cast<const float4*>(base + (size_t)(i + 1) * H_)[t];
    const float* hb = hrow[i & 1];
    const float4* hb4 = reinterpret_cast<const float4*>(&hb[qq * HP]);
    float4 p0 = make_float4(0, 0, 0, 0), p1 = make_float4(0, 0, 0, 0);
#pragma unroll
    for (int q = 0; q < 16; ++q) {
      float4 hq = hb4[q];
      p0.x += w0[q].x * hq.x; p0.y += w0[q].y * hq.y;
      p0.z += w0[q].z * hq.z; p0.w += w0[q].w * hq.w;
      p1.x += w1[q].x * hq.x; p1.y += w1[q].y * hq.y;
      p1.z += w1[q].z * hq.z; p1.w += w1[q].w * hq.w;
    }
    float sc0 = quad_reduce_add((p0.x + p0.y) + (p0.z + p0.w)) + ba0;
    float sc1 = quad_reduce_add((p1.x + p1.y) + (p1.z + p1.w)) + ba1;
    float hv0 = hb[SWI(o0)], hv1 = hb[SWI(o1)];
    {
      float mn = fmaxf(m0, sc0);
      float sc = __expf(m0 - mn), e = __expf(sc0 - mn);
      l0 = l0 * sc + e; N0 = N0 * sc + e * hv0; m0 = mn;
    }
    {
      float mn = fmaxf(m1, sc1);
      float sc = __expf(m1 - mn), e = __expf(sc1 - mn);
      l1 = l1 * sc + e; N1 = N1 * sc + e * hv1; m1 = mn;
    }
    if (pf) reinterpret_cast<float4*>(&hrow[(i + 1) & 1][(t >> 4) * HP])[t & 15] = nv;
    __syncthreads();
  }
  if (qq == 0) {
    float* pb = part + (size_t)blockIdx.x * 3 * H_;
    pb[o0] = m0;           pb[o1] = m1;
    pb[H_ + o0] = l0;      pb[H_ + o1] = l1;
    pb[2 * H_ + o0] = N0;  pb[2 * H_ + o1] = N1;
  }
}

// ---------------------------------------------------------------------------
// K3b: merge 4 sequence-quarter partials -> context[b,h] = N/l
// ---------------------------------------------------------------------------
__global__ __launch_bounds__(256) void attn_merge(const float* __restrict__ part,
                                                  float* __restrict__ ctx) {
  const int b = blockIdx.x, t = threadIdx.x;
  float m = -3.0e38f, l = 0.f, N = 0.f;
#pragma unroll
  for (int j = 0; j < 4; ++j) {
    const float* pb = part + (size_t)(b * 4 + j) * 3 * H_;
    float m2 = pb[t], l2 = pb[H_ + t], N2 = pb[2 * H_ + t];
    float mn = fmaxf(m, m2);
    float A1 = __expf(m - mn), A2 = __expf(m2 - mn);
    l = l * A1 + l2 * A2;
    N = N * A1 + N2 * A2;
    m = mn;
  }
  ctx[b * H_ + t] = N / l;
}

// ---------------------------------------------------------------------------
// K4: out = (hs + context) @ Wfc^T + bfc, in place over d_out. 16 rows/block
// staged (+ctx) in staggered LDS; same (vg,qq) split; 8192 blocks.
// ---------------------------------------------------------------------------
__global__ __launch_bounds__(512, 2) void out_gemm(float* __restrict__ data,
                                                   const float* __restrict__ Wfc,
                                                   const float* __restrict__ bfc,
                                                   const float* __restrict__ ctx) {
  const int t = threadIdx.x;
  const int tile = blockIdx.x;  // 16 rows each; 64 tiles per batch
  const int b = tile >> 6;
  const size_t r0 = (size_t)tile * 16;
  const int qq = t & 3, vg = t >> 2;
  const int v0 = vg, v1 = vg + 128;
  const int kb = qq * 64;

  float4 w0[16], w1[16];
  {
    const float4* W0 = reinterpret_cast<const float4*>(Wfc + v0 * H_ + kb);
    const float4* W1 = reinterpret_cast<const float4*>(Wfc + v1 * H_ + kb);
#pragma unroll
    for (int q = 0; q < 16; ++q) { w0[q] = W0[q]; w1[q] = W1[q]; }
  }

  __shared__ __align__(16) float comb[16][4 * HP];
  {
    const float4* src = reinterpret_cast<const float4*>(data + r0 * H_);
    const float4* cx4 = reinterpret_cast<const float4*>(ctx + b * H_);
#pragma unroll
    for (int u = 0; u < 2; ++u) {
      int f4 = t + u * 512;  // [0,1024): row = f4/64, float4-col = f4%64
      int row = f4 >> 6, c4 = f4 & 63;
      float4 v = src[f4];
      float4 c = cx4[c4];
      v.x += c.x; v.y += c.y; v.z += c.z; v.w += c.w;
      reinterpret_cast<float4*>(&comb[row][(c4 >> 4) * HP])[c4 & 15] = v;
    }
  }
  const float bv0 = bfc[v0], bv1 = bfc[v1];
  __syncthreads();

#pragma unroll 1
  for (int r = 0; r < 16; ++r) {
    const float4* hb4 = reinterpret_cast<const float4*>(&comb[r][qq * HP]);
    float4 p0 = make_float4(0, 0, 0, 0), p1 = make_float4(0, 0, 0, 0);
#pragma unroll
    for (int q = 0; q < 16; ++q) {
      float4 hq = hb4[q];
      p0.x += w0[q].x * hq.x; p0.y += w0[q].y * hq.y;
      p0.z += w0[q].z * hq.z; p0.w += w0[q].w * hq.w;
      p1.x += w1[q].x * hq.x; p1.y += w1[q].y * hq.y;
      p1.z += w1[q].z * hq.z; p1.w += w1[q].w * hq.w;
    }
    float d0 = quad_reduce_add((p0.x + p0.y) + (p0.z + p0.w)) + bv0;
    float d1 = quad_reduce_add((p1.x + p1.y) + (p1.z + p1.w)) + bv1;
    if (qq == 0) {
      data[(r0 + r) * H_ + v0] = d0;
      data[(r0 + r) * H_ + v1] = d1;
    }
  }
}

// ---------------------------------------------------------------------------
extern "C" void kernel_launch(void* const* d_in, const int* in_sizes, int n_in,
                              void* d_out, int out_size, void* d_ws, size_t ws_size,
                              hipStream_t stream) {
  const int* x = (const int*)d_in[0];
  const float* embed = (const float*)d_in[1];
  const float* Wxh = (const float*)d_in[2];
  const float* bxh = (const float*)d_in[3];
  const float* Whh = (const float*)d_in[4];
  const float* bhh = (const float*)d_in[5];
  const float* Wattn = (const float*)d_in[6];
  const float* battn = (const float*)d_in[7];
  const float* Wfc = (const float*)d_in[8];
  const float* bfc = (const float*)d_in[9];
  float* out = (float*)d_out;

  float* A = (float*)d_ws;                 // V*H
  float* part = A + V_ * H_;               // B*4*3*H
  float* ctx = part + B_ * 4 * 3 * H_;     // B*H

  prep_A<<<V_, 512, 0, stream>>>(embed, Wxh, bxh, bhh, A);
  rnn_fwd<<<B_, 512, 0, stream>>>(x, A, Whh, out);
  attn_part_k<<<B_ * 4, 512, 0, stream>>>(out, Wattn, battn, part);
  attn_merge<<<B_, 256, 0, stream>>>(part, ctx);
  out_gemm<<<B_ * S_ / 16, 512, 0, stream>>>(out, Wfc, bfc, ctx);
}